// Round 4
// baseline (423.470 us; speedup 1.0000x reference)
//
#include <hip/hip_runtime.h>

typedef float vfloat4 __attribute__((ext_vector_type(4)));
typedef int   vint4   __attribute__((ext_vector_type(4)));

// u1[bc[k]] = w1[k] * u[bc[k]]
__global__ void scatter_u1_kernel(const float* __restrict__ u,
                                  const float* __restrict__ w1,
                                  const int* __restrict__ bc,
                                  float* __restrict__ u1, int n) {
    int k = blockIdx.x * blockDim.x + threadIdx.x;
    if (k < n) {
        int idx = bc[k];
        u1[idx] = w1[k] * u[idx];
    }
}

// Phase A: 8 threads/element, compute fe_i, coalesced write to febuf[t].
__global__ void compute_fe_kernel(const float* __restrict__ u1,
                                  const int* __restrict__ edof,
                                  const float* __restrict__ stiff,
                                  float* __restrict__ febuf, int nelem) {
    int t = blockIdx.x * blockDim.x + threadIdx.x;
    int e = t >> 3;
    if (e >= nelem) return;
    int i = t & 7;

    int idx = __builtin_nontemporal_load(edof + t);
    float ue = u1[idx];

    const vfloat4* Kr = (const vfloat4*)(stiff + (size_t)e * 64 + (size_t)i * 8);
    vfloat4 k0 = __builtin_nontemporal_load(Kr);
    vfloat4 k1 = __builtin_nontemporal_load(Kr + 1);

    float fe;
    fe  = k0.x * __shfl(ue, 0, 8);
    fe += k0.y * __shfl(ue, 1, 8);
    fe += k0.z * __shfl(ue, 2, 8);
    fe += k0.w * __shfl(ue, 3, 8);
    fe += k1.x * __shfl(ue, 4, 8);
    fe += k1.y * __shfl(ue, 5, 8);
    fe += k1.z * __shfl(ue, 6, 8);
    fe += k1.w * __shfl(ue, 7, 8);

    __builtin_nontemporal_store(fe, febuf + t);
}

// Phase B: pure atomic scatter. 4 entries/thread via x4 vector loads.
__global__ void scatter_add_kernel(const int* __restrict__ edof,
                                   const float* __restrict__ febuf,
                                   float* __restrict__ F, int n4) {
    int t = blockIdx.x * blockDim.x + threadIdx.x;
    if (t >= n4) return;
    vint4   idx = __builtin_nontemporal_load((const vint4*)edof + t);
    vfloat4 fe  = __builtin_nontemporal_load((const vfloat4*)febuf + t);
    unsafeAtomicAdd(&F[idx.x], fe.x);
    unsafeAtomicAdd(&F[idx.y], fe.y);
    unsafeAtomicAdd(&F[idx.z], fe.z);
    unsafeAtomicAdd(&F[idx.w], fe.w);
}

// Fallback (fused) if ws too small for febuf.
__global__ void elem_assemble_kernel(const float* __restrict__ u1,
                                     const int* __restrict__ edof,
                                     const float* __restrict__ stiff,
                                     float* __restrict__ F, int nelem) {
    int t = blockIdx.x * blockDim.x + threadIdx.x;
    int e = t >> 3;
    if (e >= nelem) return;
    int i = t & 7;
    int idx = __builtin_nontemporal_load(edof + t);
    float ue = u1[idx];
    const vfloat4* Kr = (const vfloat4*)(stiff + (size_t)e * 64 + (size_t)i * 8);
    vfloat4 k0 = __builtin_nontemporal_load(Kr);
    vfloat4 k1 = __builtin_nontemporal_load(Kr + 1);
    float fe;
    fe  = k0.x * __shfl(ue, 0, 8);
    fe += k0.y * __shfl(ue, 1, 8);
    fe += k0.z * __shfl(ue, 2, 8);
    fe += k0.w * __shfl(ue, 3, 8);
    fe += k1.x * __shfl(ue, 4, 8);
    fe += k1.y * __shfl(ue, 5, 8);
    fe += k1.z * __shfl(ue, 6, 8);
    fe += k1.w * __shfl(ue, 7, 8);
    unsafeAtomicAdd(&F[idx], fe);
}

extern "C" void kernel_launch(void* const* d_in, const int* in_sizes, int n_in,
                              void* d_out, int out_size, void* d_ws, size_t ws_size,
                              hipStream_t stream) {
    const float* u     = (const float*)d_in[0];
    const float* w1    = (const float*)d_in[1];
    const int*   bc    = (const int*)d_in[2];
    const int*   edof  = (const int*)d_in[3];
    const float* stiff = (const float*)d_in[4];
    float* F  = (float*)d_out;
    float* u1 = (float*)d_ws;

    int ndof  = in_sizes[0];
    int nbc   = in_sizes[2];
    int total = in_sizes[3];      // NELEM * 8
    int nelem = total / 8;

    (void)hipMemsetAsync(F,  0, (size_t)ndof * sizeof(float), stream);
    (void)hipMemsetAsync(u1, 0, (size_t)ndof * sizeof(float), stream);

    scatter_u1_kernel<<<(nbc + 255) / 256, 256, 0, stream>>>(u, w1, bc, u1, nbc);

    size_t need = (size_t)ndof * 4 + (size_t)total * 4;
    if (ws_size >= need) {
        float* febuf = u1 + ndof;
        compute_fe_kernel<<<(total + 255) / 256, 256, 0, stream>>>(
            u1, edof, stiff, febuf, nelem);
        int n4 = total / 4;
        scatter_add_kernel<<<(n4 + 255) / 256, 256, 0, stream>>>(
            edof, febuf, F, n4);
    } else {
        elem_assemble_kernel<<<(total + 255) / 256, 256, 0, stream>>>(
            u1, edof, stiff, F, nelem);
    }
}

// Round 5
// 338.736 us; speedup vs baseline: 1.2501x; 1.2501x over previous
//
#include <hip/hip_runtime.h>

typedef float vfloat4 __attribute__((ext_vector_type(4)));

#define BSHIFT 12
#define BSIZE  4096      // DOFs per bucket (16 KB LDS accumulator)
#define G1     512       // workgroups for hist/scatter passes
#define TPB    256

// u1[bc[k]] = w1[k] * u[bc[k]]
__global__ void scatter_u1_kernel(const float* __restrict__ u,
                                  const float* __restrict__ w1,
                                  const int* __restrict__ bc,
                                  float* __restrict__ u1, int n) {
    int k = blockIdx.x * blockDim.x + threadIdx.x;
    if (k < n) {
        int idx = bc[k];
        u1[idx] = w1[k] * u[idx];
    }
}

// 8 threads/element: fe_i = sum_j K[i][j]*ue_j, coalesced store to febuf.
__global__ void compute_fe_kernel(const float* __restrict__ u1,
                                  const int* __restrict__ edof,
                                  const float* __restrict__ stiff,
                                  float* __restrict__ febuf, int nelem) {
    int t = blockIdx.x * blockDim.x + threadIdx.x;
    int e = t >> 3;
    if (e >= nelem) return;
    int i = t & 7;

    int idx = __builtin_nontemporal_load(edof + t);
    float ue = u1[idx];

    const vfloat4* Kr = (const vfloat4*)(stiff + (size_t)e * 64 + (size_t)i * 8);
    vfloat4 k0 = __builtin_nontemporal_load(Kr);
    vfloat4 k1 = __builtin_nontemporal_load(Kr + 1);

    float fe;
    fe  = k0.x * __shfl(ue, 0, 8);
    fe += k0.y * __shfl(ue, 1, 8);
    fe += k0.z * __shfl(ue, 2, 8);
    fe += k0.w * __shfl(ue, 3, 8);
    fe += k1.x * __shfl(ue, 4, 8);
    fe += k1.y * __shfl(ue, 5, 8);
    fe += k1.z * __shfl(ue, 6, 8);
    fe += k1.w * __shfl(ue, 7, 8);

    __builtin_nontemporal_store(fe, febuf + t);
}

// Pass 1: per-workgroup bucket histogram (LDS int atomics only).
__global__ void hist_kernel(const int* __restrict__ edof,
                            int* __restrict__ cnt,   // [nb][G1]
                            int total, int nb, int chunk) {
    __shared__ int h[256];
    int wg = blockIdx.x;
    if (threadIdx.x < nb) h[threadIdx.x] = 0;
    __syncthreads();
    int k0 = wg * chunk;
    int k1 = min(k0 + chunk, total);
    for (int k = k0 + threadIdx.x; k < k1; k += TPB) {
        int b = edof[k] >> BSHIFT;
        atomicAdd(&h[b], 1);
    }
    __syncthreads();
    if (threadIdx.x < nb) cnt[threadIdx.x * G1 + wg] = h[threadIdx.x];
}

// Pass 1b: per-bucket exclusive scan over the G1 workgroup counts. 1 wave/bucket.
__global__ void scan_bucket_kernel(const int* __restrict__ cnt,  // [nb][G1]
                                   int* __restrict__ wgoff,      // [nb][G1]
                                   int* __restrict__ btot) {     // [nb]
    int b = blockIdx.x;
    int lane = threadIdx.x;          // 0..63
    const int per = G1 / 64;         // 8 values per lane
    int v[per];
    int s = 0;
    for (int j = 0; j < per; ++j) { v[j] = cnt[b * G1 + lane * per + j]; s += v[j]; }
    int incl = s;
    for (int off = 1; off < 64; off <<= 1) {
        int n = __shfl_up(incl, off, 64);
        if (lane >= off) incl += n;
    }
    int run = incl - s;              // exclusive prefix of this lane's group
    for (int j = 0; j < per; ++j) { wgoff[b * G1 + lane * per + j] = run; run += v[j]; }
    if (lane == 63) btot[b] = incl;
}

// Pass 1c: serial exclusive scan of bucket totals (nb <= 256, trivial).
__global__ void scan_total_kernel(const int* __restrict__ btot,
                                  int* __restrict__ bstart, int nb) {
    if (blockIdx.x == 0 && threadIdx.x == 0) {
        int s = 0;
        for (int b = 0; b < nb; ++b) { bstart[b] = s; s += btot[b]; }
        bstart[nb] = s;
    }
}

// Pass 2: scatter packed (idx, fe) pairs into bucket-sorted order.
// Positions are conflict-free across workgroups (from the scans); only LDS
// int atomics for intra-workgroup ranks. No global atomics.
__global__ void scatter_pairs_kernel(const int* __restrict__ edof,
                                     const float* __restrict__ febuf,
                                     const int* __restrict__ wgoff, // [nb][G1]
                                     const int* __restrict__ bstart,
                                     unsigned long long* __restrict__ pairs,
                                     int total, int nb, int chunk) {
    __shared__ int base[256];
    int wg = blockIdx.x;
    if (threadIdx.x < nb)
        base[threadIdx.x] = bstart[threadIdx.x] + wgoff[threadIdx.x * G1 + wg];
    __syncthreads();
    int k0 = wg * chunk;
    int k1 = min(k0 + chunk, total);
    for (int k = k0 + threadIdx.x; k < k1; k += TPB) {
        int idx = __builtin_nontemporal_load(edof + k);
        float fe = __builtin_nontemporal_load(febuf + k);
        int b = idx >> BSHIFT;
        int pos = atomicAdd(&base[b], 1);
        pairs[pos] = ((unsigned long long)(unsigned)idx << 32) | __float_as_uint(fe);
    }
}

// Pass 3: one workgroup per bucket. LDS fp32 accumulate (ds_add_f32),
// then plain coalesced stores — F fully covered, no memset needed.
__global__ void bucket_reduce_kernel(const unsigned long long* __restrict__ pairs,
                                     const int* __restrict__ bstart,
                                     float* __restrict__ F, int ndof) {
    __shared__ float acc[BSIZE];
    int b = blockIdx.x;
    for (int j = threadIdx.x; j < BSIZE; j += TPB) acc[j] = 0.0f;
    __syncthreads();
    int k0 = bstart[b], k1 = bstart[b + 1];
    for (int k = k0 + threadIdx.x; k < k1; k += TPB) {
        unsigned long long p = pairs[k];
        int idx = (int)(p >> 32);
        float fe = __uint_as_float((unsigned)p);
        atomicAdd(&acc[idx & (BSIZE - 1)], fe);
    }
    __syncthreads();
    int gbase = b << BSHIFT;
    for (int j = threadIdx.x; j < BSIZE; j += TPB) {
        int g = gbase + j;
        if (g < ndof) F[g] = acc[j];
    }
}

// Fallback (fused atomics) if ws too small.
__global__ void elem_assemble_kernel(const float* __restrict__ u1,
                                     const int* __restrict__ edof,
                                     const float* __restrict__ stiff,
                                     float* __restrict__ F, int nelem) {
    int t = blockIdx.x * blockDim.x + threadIdx.x;
    int e = t >> 3;
    if (e >= nelem) return;
    int i = t & 7;
    int idx = __builtin_nontemporal_load(edof + t);
    float ue = u1[idx];
    const vfloat4* Kr = (const vfloat4*)(stiff + (size_t)e * 64 + (size_t)i * 8);
    vfloat4 k0 = __builtin_nontemporal_load(Kr);
    vfloat4 k1 = __builtin_nontemporal_load(Kr + 1);
    float fe;
    fe  = k0.x * __shfl(ue, 0, 8);
    fe += k0.y * __shfl(ue, 1, 8);
    fe += k0.z * __shfl(ue, 2, 8);
    fe += k0.w * __shfl(ue, 3, 8);
    fe += k1.x * __shfl(ue, 4, 8);
    fe += k1.y * __shfl(ue, 5, 8);
    fe += k1.z * __shfl(ue, 6, 8);
    fe += k1.w * __shfl(ue, 7, 8);
    unsafeAtomicAdd(&F[idx], fe);
}

extern "C" void kernel_launch(void* const* d_in, const int* in_sizes, int n_in,
                              void* d_out, int out_size, void* d_ws, size_t ws_size,
                              hipStream_t stream) {
    const float* u     = (const float*)d_in[0];
    const float* w1    = (const float*)d_in[1];
    const int*   bc    = (const int*)d_in[2];
    const int*   edof  = (const int*)d_in[3];
    const float* stiff = (const float*)d_in[4];
    float* F = (float*)d_out;

    int ndof  = in_sizes[0];
    int nbc   = in_sizes[2];
    int total = in_sizes[3];      // NELEM * 8
    int nelem = total / 8;
    int nb    = (ndof + BSIZE - 1) >> BSHIFT;

    // Carve workspace (256 B aligned chunks).
    char* w = (char*)d_ws;
    size_t o = 0;
    auto take = [&](size_t nbytes) -> char* {
        char* p = w + o;
        o += (nbytes + 255) & ~(size_t)255;
        return p;
    };
    float* u1    = (float*)take((size_t)ndof * 4);
    float* febuf = (float*)take((size_t)total * 4);
    unsigned long long* pairs = (unsigned long long*)take((size_t)total * 8);
    int* cnt    = (int*)take((size_t)nb * G1 * 4);
    int* wgoff  = (int*)take((size_t)nb * G1 * 4);
    int* btot   = (int*)take((size_t)nb * 4);
    int* bstart = (int*)take((size_t)(nb + 1) * 4);

    (void)hipMemsetAsync(u1, 0, (size_t)ndof * sizeof(float), stream);
    scatter_u1_kernel<<<(nbc + TPB - 1) / TPB, TPB, 0, stream>>>(u, w1, bc, u1, nbc);

    if (o <= ws_size && nb <= 256) {
        compute_fe_kernel<<<(total + TPB - 1) / TPB, TPB, 0, stream>>>(
            u1, edof, stiff, febuf, nelem);

        int chunk = (total + G1 - 1) / G1;
        hist_kernel<<<G1, TPB, 0, stream>>>(edof, cnt, total, nb, chunk);
        scan_bucket_kernel<<<nb, 64, 0, stream>>>(cnt, wgoff, btot);
        scan_total_kernel<<<1, 64, 0, stream>>>(btot, bstart, nb);
        scatter_pairs_kernel<<<G1, TPB, 0, stream>>>(
            edof, febuf, wgoff, bstart, pairs, total, nb, chunk);
        bucket_reduce_kernel<<<nb, TPB, 0, stream>>>(pairs, bstart, F, ndof);
    } else {
        (void)hipMemsetAsync(F, 0, (size_t)ndof * sizeof(float), stream);
        elem_assemble_kernel<<<(total + TPB - 1) / TPB, TPB, 0, stream>>>(
            u1, edof, stiff, F, nelem);
    }
}